// Round 3
// baseline (481.029 us; speedup 1.0000x reference)
//
#include <hip/hip_runtime.h>
#include <hip/hip_fp16.h>
#include <stdint.h>

#define NNODES 50000
#define NEDGES 800000
#define NHID 96
#define NCLS 16

// ---------- JAX Threefry-2x32 (Random123 20-round, matches jax._src.prng) ----------
__host__ __device__ inline void tf2x32(uint32_t k0, uint32_t k1, uint32_t x0, uint32_t x1,
                                       uint32_t& o0, uint32_t& o1) {
  uint32_t k2 = k0 ^ k1 ^ 0x1BD11BDAu;
#define TFROT(v, r) (((v) << (r)) | ((v) >> (32 - (r))))
#define TFR(r) { x0 += x1; x1 = TFROT(x1, r); x1 ^= x0; }
  x0 += k0; x1 += k1;
  TFR(13) TFR(15) TFR(26) TFR(6)
  x0 += k1; x1 += k2 + 1u;
  TFR(17) TFR(29) TFR(16) TFR(24)
  x0 += k2; x1 += k0 + 2u;
  TFR(13) TFR(15) TFR(26) TFR(6)
  x0 += k0; x1 += k1 + 3u;
  TFR(17) TFR(29) TFR(16) TFR(24)
  x0 += k1; x1 += k2 + 4u;
  TFR(13) TFR(15) TFR(26) TFR(6)
  x0 += k2; x1 += k0 + 5u;
  o0 = x0; o1 = x1;
#undef TFR
#undef TFROT
}

__host__ __device__ inline uint32_t pack_sw(int s, float w) {
  return ((uint32_t)s << 16) | (uint32_t)__half_as_ushort(__float2half_rn(w));
}

// ---------- pass 1: degrees + per-edge slot (CSR local index) ----------
__global__ __launch_bounds__(256) void count_kernel(
    const int* __restrict__ src, const int* __restrict__ dst,
    int* __restrict__ odeg, int* __restrict__ ideg, int* __restrict__ slot) {
  int e = blockIdx.x * 256 + threadIdx.x;
  if (e >= NEDGES) return;
  atomicAdd(&odeg[src[e]], 1);
  slot[e] = atomicAdd(&ideg[dst[e]], 1);   // sequential 4B write of slot
}

// ---------- exclusive prefix sum of ideg -> row_ptr (single block) ----------
__global__ __launch_bounds__(1024) void scan_kernel(
    const int* __restrict__ ideg, int* __restrict__ row_ptr) {
  __shared__ int lds[1024];
  const int tid = threadIdx.x;
  const int CHUNK = (NNODES + 1023) / 1024;   // 49
  const int base = tid * CHUNK;
  int s = 0;
  for (int i = 0; i < CHUNK; ++i) {
    int idx = base + i;
    if (idx < NNODES) s += ideg[idx];
  }
  lds[tid] = s;
  __syncthreads();
  for (int off = 1; off < 1024; off <<= 1) {
    int v = (tid >= off) ? lds[tid - off] : 0;
    __syncthreads();
    lds[tid] += v;
    __syncthreads();
  }
  int run = lds[tid] - s;                     // exclusive
  for (int i = 0; i < CHUNK; ++i) {
    int idx = base + i;
    if (idx < NNODES) { row_ptr[idx] = run; run += ideg[idx]; }
  }
  if (tid == 0) row_ptr[NNODES] = NEDGES;
}

__global__ __launch_bounds__(256) void inv_kernel(
    const int* __restrict__ odeg, const int* __restrict__ ideg,
    float* __restrict__ inv_o, float* __restrict__ inv_i) {
  int n = blockIdx.x * 256 + threadIdx.x;
  if (n >= NNODES) return;
  inv_o[n] = rsqrtf(fmaxf((float)odeg[n], 1.0f));
  inv_i[n] = rsqrtf(fmaxf((float)ideg[n], 1.0f));
}

// ---------- pass 2: atomic-free scatter into dense packed CSR ----------
__global__ __launch_bounds__(256) void fill2_kernel(
    const int* __restrict__ src, const int* __restrict__ dst, const float* __restrict__ ew,
    const int* __restrict__ row_ptr, const int* __restrict__ slot,
    uint32_t* __restrict__ csr) {
  int e = blockIdx.x * 256 + threadIdx.x;
  if (e >= NEDGES) return;
  int pos = row_ptr[dst[e]] + slot[e];
  csr[pos] = pack_sw(src[e], ew[e]);
}

// ---------- dropout (JAX partitionable threefry bits) + D_out^-1/2 scale ----------
__global__ __launch_bounds__(256) void drop_kernel(
    const float* __restrict__ h, const float* __restrict__ inv_o,
    float* __restrict__ X, uint32_t k0, uint32_t k1) {
  int j = blockIdx.x * 256 + threadIdx.x;
  if (j >= NNODES * NHID) return;
  uint32_t o0, o1;
  tf2x32(k0, k1, 0u, (uint32_t)j, o0, o1);      // counter = uint64 j: hi=0, lo=j
  uint32_t bits = o0 ^ o1;                      // partitionable 32-bit path
  int n = j / NHID;
  float v = ((bits >> 31) == 0u) ? h[j] * (2.0f * inv_o[n]) : 0.0f;
  X[j] = v;
}

// ---------- GEMM96: Y[N,96] = X[N,96] @ W[96,96], LDS-staged W ----------
__global__ __launch_bounds__(256) void gemm96_kernel(
    const float* __restrict__ X, const float* __restrict__ W, float* __restrict__ Y) {
  __shared__ float Wl[96 * 96];
  const int tid = threadIdx.x;
  {
    const float4* Wg = (const float4*)W;
    float4* Ws = (float4*)Wl;
#pragma unroll
    for (int i = 0; i < 9; ++i)
      Ws[tid + i * 256] = Wg[tid + i * 256];
  }
  __syncthreads();

  const int cg = tid & 7;
  const int rq = tid >> 3;
  const int row0 = blockIdx.x * 128 + rq * 4;
  const int c0 = cg * 12;

  float acc[4][12];
#pragma unroll
  for (int r = 0; r < 4; ++r)
#pragma unroll
    for (int c = 0; c < 12; ++c) acc[r][c] = 0.f;

  const float* xr[4];
#pragma unroll
  for (int r = 0; r < 4; ++r) {
    int rr = row0 + r; if (rr > NNODES - 1) rr = NNODES - 1;
    xr[r] = X + (size_t)rr * 96;
  }

  for (int k = 0; k < 96; k += 4) {
    float4 x4[4];
#pragma unroll
    for (int r = 0; r < 4; ++r) x4[r] = *(const float4*)(xr[r] + k);
#pragma unroll
    for (int kk = 0; kk < 4; ++kk) {
      const float4* wp = (const float4*)(Wl + (k + kk) * 96 + c0);
      float4 w0 = wp[0], w1 = wp[1], w2 = wp[2];
      float xv[4] = { (&x4[0].x)[kk], (&x4[1].x)[kk], (&x4[2].x)[kk], (&x4[3].x)[kk] };
#pragma unroll
      for (int r = 0; r < 4; ++r) {
        acc[r][0]  += xv[r] * w0.x; acc[r][1]  += xv[r] * w0.y;
        acc[r][2]  += xv[r] * w0.z; acc[r][3]  += xv[r] * w0.w;
        acc[r][4]  += xv[r] * w1.x; acc[r][5]  += xv[r] * w1.y;
        acc[r][6]  += xv[r] * w1.z; acc[r][7]  += xv[r] * w1.w;
        acc[r][8]  += xv[r] * w2.x; acc[r][9]  += xv[r] * w2.y;
        acc[r][10] += xv[r] * w2.z; acc[r][11] += xv[r] * w2.w;
      }
    }
  }

#pragma unroll
  for (int r = 0; r < 4; ++r) {
    int rr = row0 + r;
    if (rr < NNODES) {
      float* yp = Y + (size_t)rr * 96 + c0;
      *(float4*)(yp + 0) = make_float4(acc[r][0], acc[r][1], acc[r][2], acc[r][3]);
      *(float4*)(yp + 4) = make_float4(acc[r][4], acc[r][5], acc[r][6], acc[r][7]);
      *(float4*)(yp + 8) = make_float4(acc[r][8], acc[r][9], acc[r][10], acc[r][11]);
    }
  }
}

// ---------- GEMM16: Y[N,16] = X[N,96] @ W[96,16], LDS-staged W ----------
__global__ __launch_bounds__(256) void gemm16_kernel(
    const float* __restrict__ X, const float* __restrict__ W, float* __restrict__ Y) {
  __shared__ float Wl[96 * 16];
  const int tid = threadIdx.x;
  {
    const float4* Wg = (const float4*)W;
    float4* Ws = (float4*)Wl;
    for (int i = tid; i < 384; i += 256) Ws[i] = Wg[i];
  }
  __syncthreads();

  const int row0 = blockIdx.x * 512 + tid * 2;
  const float* xr[2];
#pragma unroll
  for (int r = 0; r < 2; ++r) {
    int rr = row0 + r; if (rr > NNODES - 1) rr = NNODES - 1;
    xr[r] = X + (size_t)rr * 96;
  }

  float acc[2][16];
#pragma unroll
  for (int r = 0; r < 2; ++r)
#pragma unroll
    for (int c = 0; c < 16; ++c) acc[r][c] = 0.f;

  for (int k = 0; k < 96; k += 4) {
    float4 x4[2];
#pragma unroll
    for (int r = 0; r < 2; ++r) x4[r] = *(const float4*)(xr[r] + k);
#pragma unroll
    for (int kk = 0; kk < 4; ++kk) {
      const float4* wp = (const float4*)(Wl + (k + kk) * 16);
      float4 w0 = wp[0], w1 = wp[1], w2 = wp[2], w3 = wp[3];
#pragma unroll
      for (int r = 0; r < 2; ++r) {
        float xv = (&x4[r].x)[kk];
        acc[r][0]  += xv * w0.x; acc[r][1]  += xv * w0.y;
        acc[r][2]  += xv * w0.z; acc[r][3]  += xv * w0.w;
        acc[r][4]  += xv * w1.x; acc[r][5]  += xv * w1.y;
        acc[r][6]  += xv * w1.z; acc[r][7]  += xv * w1.w;
        acc[r][8]  += xv * w2.x; acc[r][9]  += xv * w2.y;
        acc[r][10] += xv * w2.z; acc[r][11] += xv * w2.w;
        acc[r][12] += xv * w3.x; acc[r][13] += xv * w3.y;
        acc[r][14] += xv * w3.z; acc[r][15] += xv * w3.w;
      }
    }
  }

#pragma unroll
  for (int r = 0; r < 2; ++r) {
    int rr = row0 + r;
    if (rr < NNODES) {
      float4* yp = (float4*)(Y + (size_t)rr * 16);
      yp[0] = make_float4(acc[r][0], acc[r][1], acc[r][2], acc[r][3]);
      yp[1] = make_float4(acc[r][4], acc[r][5], acc[r][6], acc[r][7]);
      yp[2] = make_float4(acc[r][8], acc[r][9], acc[r][10], acc[r][11]);
      yp[3] = make_float4(acc[r][12], acc[r][13], acc[r][14], acc[r][15]);
    }
  }
}

// ---------- per-dst CSR gather of 96-dim messages + inv_in*bias+ReLU ----------
__global__ __launch_bounds__(256) void gather96_kernel(
    const float* __restrict__ Y, const uint32_t* __restrict__ csr,
    const int* __restrict__ row_ptr, const float* __restrict__ inv_in,
    const float* __restrict__ bias, float* __restrict__ hout) {
  int tid = blockIdx.x * 256 + threadIdx.x;
  int n = tid / 24;
  int q = tid - n * 24;        // float4 chunk within the 96-dim row
  if (n >= NNODES) return;
  int beg = row_ptr[n], end = row_ptr[n + 1];
  float ax = 0.f, ay = 0.f, az = 0.f, aw = 0.f;
  for (int p = beg; p < end; ++p) {
    uint32_t pr = csr[p];
    int s = pr >> 16;
    float w = __half2float(__ushort_as_half((unsigned short)(pr & 0xFFFFu)));
    float4 v = *(const float4*)(Y + (size_t)s * 96 + q * 4);
    ax += v.x * w; ay += v.y * w; az += v.z * w; aw += v.w * w;
  }
  float iv = inv_in[n];
  float4 bb = *(const float4*)(bias + q * 4);
  float4 o;
  o.x = fmaxf(ax * iv + bb.x, 0.f);
  o.y = fmaxf(ay * iv + bb.y, 0.f);
  o.z = fmaxf(az * iv + bb.z, 0.f);
  o.w = fmaxf(aw * iv + bb.w, 0.f);
  *(float4*)(hout + (size_t)n * 96 + q * 4) = o;
}

// ---------- layer 2: CSR gather 16-dim + bias + log_softmax ----------
__global__ __launch_bounds__(256) void gather16_lsm_kernel(
    const float* __restrict__ Y2, const uint32_t* __restrict__ csr,
    const int* __restrict__ row_ptr, const float* __restrict__ inv_in,
    const float* __restrict__ b2, float* __restrict__ out) {
  int n = blockIdx.x * 256 + threadIdx.x;
  if (n >= NNODES) return;
  int beg = row_ptr[n], end = row_ptr[n + 1];
  float4 a0 = {0,0,0,0}, a1 = {0,0,0,0}, a2 = {0,0,0,0}, a3 = {0,0,0,0};
  for (int p = beg; p < end; ++p) {
    uint32_t pr = csr[p];
    int s = pr >> 16;
    float w = __half2float(__ushort_as_half((unsigned short)(pr & 0xFFFFu)));
    const float4* y = (const float4*)(Y2 + (size_t)s * 16);
    float4 y0 = y[0], y1 = y[1], y2 = y[2], y3 = y[3];
    a0.x += y0.x * w; a0.y += y0.y * w; a0.z += y0.z * w; a0.w += y0.w * w;
    a1.x += y1.x * w; a1.y += y1.y * w; a1.z += y1.z * w; a1.w += y1.w * w;
    a2.x += y2.x * w; a2.y += y2.y * w; a2.z += y2.z * w; a2.w += y2.w * w;
    a3.x += y3.x * w; a3.y += y3.y * w; a3.z += y3.z * w; a3.w += y3.w * w;
  }
  float iv = inv_in[n];
  float v[16];
  v[0]  = a0.x * iv + b2[0];  v[1]  = a0.y * iv + b2[1];
  v[2]  = a0.z * iv + b2[2];  v[3]  = a0.w * iv + b2[3];
  v[4]  = a1.x * iv + b2[4];  v[5]  = a1.y * iv + b2[5];
  v[6]  = a1.z * iv + b2[6];  v[7]  = a1.w * iv + b2[7];
  v[8]  = a2.x * iv + b2[8];  v[9]  = a2.y * iv + b2[9];
  v[10] = a2.z * iv + b2[10]; v[11] = a2.w * iv + b2[11];
  v[12] = a3.x * iv + b2[12]; v[13] = a3.y * iv + b2[13];
  v[14] = a3.z * iv + b2[14]; v[15] = a3.w * iv + b2[15];
  float m = v[0];
#pragma unroll
  for (int i = 1; i < 16; i++) m = fmaxf(m, v[i]);
  float s = 0.f;
#pragma unroll
  for (int i = 0; i < 16; i++) s += expf(v[i] - m);
  float ls = logf(s);
  float* orow = out + (size_t)n * 16;
#pragma unroll
  for (int i = 0; i < 16; i++) orow[i] = v[i] - m - ls;
}

extern "C" void kernel_launch(void* const* d_in, const int* in_sizes, int n_in,
                              void* d_out, int out_size, void* d_ws, size_t ws_size,
                              hipStream_t stream) {
  const float* feat = (const float*)d_in[0];
  const float* ew   = (const float*)d_in[1];
  const int*   src  = (const int*)d_in[2];
  const int*   dst  = (const int*)d_in[3];
  const float* W0   = (const float*)d_in[4];
  const float* b0   = (const float*)d_in[5];
  const float* W1   = (const float*)d_in[6];
  const float* b1   = (const float*)d_in[7];
  const float* W2   = (const float*)d_in[8];
  const float* b2   = (const float*)d_in[9];
  float* out = (float*)d_out;

  char* base = (char*)d_ws;
  size_t off = 0;
  auto take = [&](size_t nbytes) {
    void* q = base + off;
    off += (nbytes + 255) & ~(size_t)255;
    return q;
  };
  int*      odeg    = (int*)take((size_t)NNODES * 4);
  int*      ideg    = (int*)take((size_t)NNODES * 4);
  int*      row_ptr = (int*)take((size_t)(NNODES + 1) * 4);
  float*    inv_o   = (float*)take((size_t)NNODES * 4);
  float*    inv_i   = (float*)take((size_t)NNODES * 4);
  int*      slot    = (int*)take((size_t)NEDGES * 4);
  uint32_t* csr     = (uint32_t*)take((size_t)NEDGES * 4);
  float*    A       = (float*)take((size_t)NNODES * NHID * 4);
  float*    B       = (float*)take((size_t)NNODES * NHID * 4);
  float*    Y2      = (float*)take((size_t)NNODES * NCLS * 4);
  (void)ws_size; (void)in_sizes; (void)n_in; (void)out_size;

  // per-layer dropout keys: fold_in(key(42), i) computed on host
  uint32_t k[3][2];
  for (uint32_t i = 0; i < 3; i++) tf2x32(0u, 42u, 0u, i, k[i][0], k[i][1]);

  hipMemsetAsync(odeg, 0, (size_t)NNODES * 4, stream);
  hipMemsetAsync(ideg, 0, (size_t)NNODES * 4, stream);
  count_kernel<<<(NEDGES + 255) / 256, 256, 0, stream>>>(src, dst, odeg, ideg, slot);
  scan_kernel<<<1, 1024, 0, stream>>>(ideg, row_ptr);
  inv_kernel<<<(NNODES + 255) / 256, 256, 0, stream>>>(odeg, ideg, inv_o, inv_i);
  fill2_kernel<<<(NEDGES + 255) / 256, 256, 0, stream>>>(src, dst, ew, row_ptr, slot, csr);

  const int NELEM = NNODES * NHID;
  const int G96 = (NNODES + 127) / 128;
  const int G16 = (NNODES + 511) / 512;

  // layer 0: feat -> A(dropped) -> B(gemm) -> A(h1)
  drop_kernel<<<(NELEM + 255) / 256, 256, 0, stream>>>(feat, inv_o, A, k[0][0], k[0][1]);
  gemm96_kernel<<<G96, 256, 0, stream>>>(A, W0, B);
  gather96_kernel<<<(NNODES * 24 + 255) / 256, 256, 0, stream>>>(B, csr, row_ptr, inv_i, b0, A);
  // layer 1: A -> B -> A -> B(h2)
  drop_kernel<<<(NELEM + 255) / 256, 256, 0, stream>>>(A, inv_o, B, k[1][0], k[1][1]);
  gemm96_kernel<<<G96, 256, 0, stream>>>(B, W1, A);
  gather96_kernel<<<(NNODES * 24 + 255) / 256, 256, 0, stream>>>(A, csr, row_ptr, inv_i, b1, B);
  // layer 2: B -> A -> Y2 -> out
  drop_kernel<<<(NELEM + 255) / 256, 256, 0, stream>>>(B, inv_o, A, k[2][0], k[2][1]);
  gemm16_kernel<<<G16, 256, 0, stream>>>(A, W2, Y2);
  gather16_lsm_kernel<<<(NNODES + 255) / 256, 256, 0, stream>>>(Y2, csr, row_ptr, inv_i, b2, out);
}

// Round 4
// 403.256 us; speedup vs baseline: 1.1929x; 1.1929x over previous
//
#include <hip/hip_runtime.h>
#include <hip/hip_fp16.h>
#include <stdint.h>

#define NNODES 50000
#define NEDGES 800000
#define NHID 96
#define NCLS 16
#define NB ((NNODES + 255) / 256)   // 196 scan blocks

// ---------- JAX Threefry-2x32 (Random123 20-round, matches jax._src.prng) ----------
__host__ __device__ inline void tf2x32(uint32_t k0, uint32_t k1, uint32_t x0, uint32_t x1,
                                       uint32_t& o0, uint32_t& o1) {
  uint32_t k2 = k0 ^ k1 ^ 0x1BD11BDAu;
#define TFROT(v, r) (((v) << (r)) | ((v) >> (32 - (r))))
#define TFR(r) { x0 += x1; x1 = TFROT(x1, r); x1 ^= x0; }
  x0 += k0; x1 += k1;
  TFR(13) TFR(15) TFR(26) TFR(6)
  x0 += k1; x1 += k2 + 1u;
  TFR(17) TFR(29) TFR(16) TFR(24)
  x0 += k2; x1 += k0 + 2u;
  TFR(13) TFR(15) TFR(26) TFR(6)
  x0 += k0; x1 += k1 + 3u;
  TFR(17) TFR(29) TFR(16) TFR(24)
  x0 += k1; x1 += k2 + 4u;
  TFR(13) TFR(15) TFR(26) TFR(6)
  x0 += k2; x1 += k0 + 5u;
  o0 = x0; o1 = x1;
#undef TFR
#undef TFROT
}

__host__ __device__ inline uint32_t pack_sw(int s, float w) {
  return ((uint32_t)s << 16) | (uint32_t)__half_as_ushort(__float2half_rn(w));
}

// ---------- pass 1: degrees + per-edge slot (CSR local index) ----------
__global__ __launch_bounds__(256) void count_kernel(
    const int* __restrict__ src, const int* __restrict__ dst,
    int* __restrict__ odeg, int* __restrict__ ideg, int* __restrict__ slot) {
  int e = blockIdx.x * 256 + threadIdx.x;
  if (e >= NEDGES) return;
  atomicAdd(&odeg[src[e]], 1);
  slot[e] = atomicAdd(&ideg[dst[e]], 1);
}

// ---------- hierarchical exclusive scan of ideg -> row_ptr ----------
__global__ __launch_bounds__(256) void scan_blocks_kernel(
    const int* __restrict__ ideg, int* __restrict__ bsum) {
  __shared__ int lds[256];
  const int tid = threadIdx.x;
  int i = blockIdx.x * 256 + tid;
  lds[tid] = (i < NNODES) ? ideg[i] : 0;
  __syncthreads();
  for (int off = 128; off > 0; off >>= 1) {
    if (tid < off) lds[tid] += lds[tid + off];
    __syncthreads();
  }
  if (tid == 0) bsum[blockIdx.x] = lds[0];
}

__global__ __launch_bounds__(256) void scan_top_kernel(
    const int* __restrict__ bsum, int* __restrict__ boff) {
  __shared__ int lds[256];
  const int tid = threadIdx.x;
  int v = (tid < NB) ? bsum[tid] : 0;
  lds[tid] = v;
  __syncthreads();
  for (int off = 1; off < 256; off <<= 1) {
    int t = (tid >= off) ? lds[tid - off] : 0;
    __syncthreads();
    lds[tid] += t;
    __syncthreads();
  }
  if (tid < NB) boff[tid] = lds[tid] - v;   // exclusive
}

__global__ __launch_bounds__(256) void scan_write_kernel(
    const int* __restrict__ ideg, const int* __restrict__ boff,
    int* __restrict__ row_ptr) {
  __shared__ int lds[256];
  const int tid = threadIdx.x;
  int i = blockIdx.x * 256 + tid;
  int v = (i < NNODES) ? ideg[i] : 0;
  lds[tid] = v;
  __syncthreads();
  for (int off = 1; off < 256; off <<= 1) {
    int t = (tid >= off) ? lds[tid - off] : 0;
    __syncthreads();
    lds[tid] += t;
    __syncthreads();
  }
  if (i < NNODES) row_ptr[i] = boff[blockIdx.x] + lds[tid] - v;
  if (i == 0) row_ptr[NNODES] = NEDGES;
}

__global__ __launch_bounds__(256) void inv_kernel(
    const int* __restrict__ odeg, const int* __restrict__ ideg,
    float* __restrict__ inv_o, float* __restrict__ inv_i) {
  int n = blockIdx.x * 256 + threadIdx.x;
  if (n >= NNODES) return;
  inv_o[n] = rsqrtf(fmaxf((float)odeg[n], 1.0f));
  inv_i[n] = rsqrtf(fmaxf((float)ideg[n], 1.0f));
}

// ---------- pass 2: atomic-free scatter into dense packed CSR ----------
__global__ __launch_bounds__(256) void fill2_kernel(
    const int* __restrict__ src, const int* __restrict__ dst, const float* __restrict__ ew,
    const int* __restrict__ row_ptr, const int* __restrict__ slot,
    uint32_t* __restrict__ csr) {
  int e = blockIdx.x * 256 + threadIdx.x;
  if (e >= NEDGES) return;
  int pos = row_ptr[dst[e]] + slot[e];
  csr[pos] = pack_sw(src[e], ew[e]);
}

// ---------- dropout (JAX partitionable threefry bits) + D_out^-1/2 scale ----------
__global__ __launch_bounds__(256) void drop_kernel(
    const float* __restrict__ h, const float* __restrict__ inv_o,
    float* __restrict__ X, uint32_t k0, uint32_t k1) {
  int j = blockIdx.x * 256 + threadIdx.x;
  if (j >= NNODES * NHID) return;
  uint32_t o0, o1;
  tf2x32(k0, k1, 0u, (uint32_t)j, o0, o1);
  uint32_t bits = o0 ^ o1;
  int n = j / NHID;
  float v = ((bits >> 31) == 0u) ? h[j] * (2.0f * inv_o[n]) : 0.0f;
  X[j] = v;
}

// ---------- GEMM96: Y[N,96] = X[N,96] @ W[96,96], LDS-staged W ----------
__global__ __launch_bounds__(256) void gemm96_kernel(
    const float* __restrict__ X, const float* __restrict__ W, float* __restrict__ Y) {
  __shared__ float Wl[96 * 96];
  const int tid = threadIdx.x;
  {
    const float4* Wg = (const float4*)W;
    float4* Ws = (float4*)Wl;
#pragma unroll
    for (int i = 0; i < 9; ++i)
      Ws[tid + i * 256] = Wg[tid + i * 256];
  }
  __syncthreads();

  const int cg = tid & 7;
  const int rq = tid >> 3;
  const int row0 = blockIdx.x * 128 + rq * 4;
  const int c0 = cg * 12;

  float acc[4][12];
#pragma unroll
  for (int r = 0; r < 4; ++r)
#pragma unroll
    for (int c = 0; c < 12; ++c) acc[r][c] = 0.f;

  const float* xr[4];
#pragma unroll
  for (int r = 0; r < 4; ++r) {
    int rr = row0 + r; if (rr > NNODES - 1) rr = NNODES - 1;
    xr[r] = X + (size_t)rr * 96;
  }

  for (int k = 0; k < 96; k += 4) {
    float4 x4[4];
#pragma unroll
    for (int r = 0; r < 4; ++r) x4[r] = *(const float4*)(xr[r] + k);
#pragma unroll
    for (int kk = 0; kk < 4; ++kk) {
      const float4* wp = (const float4*)(Wl + (k + kk) * 96 + c0);
      float4 w0 = wp[0], w1 = wp[1], w2 = wp[2];
      float xv[4] = { (&x4[0].x)[kk], (&x4[1].x)[kk], (&x4[2].x)[kk], (&x4[3].x)[kk] };
#pragma unroll
      for (int r = 0; r < 4; ++r) {
        acc[r][0]  += xv[r] * w0.x; acc[r][1]  += xv[r] * w0.y;
        acc[r][2]  += xv[r] * w0.z; acc[r][3]  += xv[r] * w0.w;
        acc[r][4]  += xv[r] * w1.x; acc[r][5]  += xv[r] * w1.y;
        acc[r][6]  += xv[r] * w1.z; acc[r][7]  += xv[r] * w1.w;
        acc[r][8]  += xv[r] * w2.x; acc[r][9]  += xv[r] * w2.y;
        acc[r][10] += xv[r] * w2.z; acc[r][11] += xv[r] * w2.w;
      }
    }
  }

#pragma unroll
  for (int r = 0; r < 4; ++r) {
    int rr = row0 + r;
    if (rr < NNODES) {
      float* yp = Y + (size_t)rr * 96 + c0;
      *(float4*)(yp + 0) = make_float4(acc[r][0], acc[r][1], acc[r][2], acc[r][3]);
      *(float4*)(yp + 4) = make_float4(acc[r][4], acc[r][5], acc[r][6], acc[r][7]);
      *(float4*)(yp + 8) = make_float4(acc[r][8], acc[r][9], acc[r][10], acc[r][11]);
    }
  }
}

// ---------- GEMM16: Y[N,16] = X[N,96] @ W[96,16], LDS-staged W ----------
__global__ __launch_bounds__(256) void gemm16_kernel(
    const float* __restrict__ X, const float* __restrict__ W, float* __restrict__ Y) {
  __shared__ float Wl[96 * 16];
  const int tid = threadIdx.x;
  {
    const float4* Wg = (const float4*)W;
    float4* Ws = (float4*)Wl;
    for (int i = tid; i < 384; i += 256) Ws[i] = Wg[i];
  }
  __syncthreads();

  const int row0 = blockIdx.x * 512 + tid * 2;
  const float* xr[2];
#pragma unroll
  for (int r = 0; r < 2; ++r) {
    int rr = row0 + r; if (rr > NNODES - 1) rr = NNODES - 1;
    xr[r] = X + (size_t)rr * 96;
  }

  float acc[2][16];
#pragma unroll
  for (int r = 0; r < 2; ++r)
#pragma unroll
    for (int c = 0; c < 16; ++c) acc[r][c] = 0.f;

  for (int k = 0; k < 96; k += 4) {
    float4 x4[2];
#pragma unroll
    for (int r = 0; r < 2; ++r) x4[r] = *(const float4*)(xr[r] + k);
#pragma unroll
    for (int kk = 0; kk < 4; ++kk) {
      const float4* wp = (const float4*)(Wl + (k + kk) * 16);
      float4 w0 = wp[0], w1 = wp[1], w2 = wp[2], w3 = wp[3];
#pragma unroll
      for (int r = 0; r < 2; ++r) {
        float xv = (&x4[r].x)[kk];
        acc[r][0]  += xv * w0.x; acc[r][1]  += xv * w0.y;
        acc[r][2]  += xv * w0.z; acc[r][3]  += xv * w0.w;
        acc[r][4]  += xv * w1.x; acc[r][5]  += xv * w1.y;
        acc[r][6]  += xv * w1.z; acc[r][7]  += xv * w1.w;
        acc[r][8]  += xv * w2.x; acc[r][9]  += xv * w2.y;
        acc[r][10] += xv * w2.z; acc[r][11] += xv * w2.w;
        acc[r][12] += xv * w3.x; acc[r][13] += xv * w3.y;
        acc[r][14] += xv * w3.z; acc[r][15] += xv * w3.w;
      }
    }
  }

#pragma unroll
  for (int r = 0; r < 2; ++r) {
    int rr = row0 + r;
    if (rr < NNODES) {
      float4* yp = (float4*)(Y + (size_t)rr * 16);
      yp[0] = make_float4(acc[r][0], acc[r][1], acc[r][2], acc[r][3]);
      yp[1] = make_float4(acc[r][4], acc[r][5], acc[r][6], acc[r][7]);
      yp[2] = make_float4(acc[r][8], acc[r][9], acc[r][10], acc[r][11]);
      yp[3] = make_float4(acc[r][12], acc[r][13], acc[r][14], acc[r][15]);
    }
  }
}

// ---------- per-dst CSR gather of 96-dim messages + inv_in*bias+ReLU ----------
__global__ __launch_bounds__(256) void gather96_kernel(
    const float* __restrict__ Y, const uint32_t* __restrict__ csr,
    const int* __restrict__ row_ptr, const float* __restrict__ inv_in,
    const float* __restrict__ bias, float* __restrict__ hout) {
  int tid = blockIdx.x * 256 + threadIdx.x;
  int n = tid / 24;
  int q = tid - n * 24;
  if (n >= NNODES) return;
  int beg = row_ptr[n], end = row_ptr[n + 1];
  float ax = 0.f, ay = 0.f, az = 0.f, aw = 0.f;
  for (int p = beg; p < end; ++p) {
    uint32_t pr = csr[p];
    int s = pr >> 16;
    float w = __half2float(__ushort_as_half((unsigned short)(pr & 0xFFFFu)));
    float4 v = *(const float4*)(Y + (size_t)s * 96 + q * 4);
    ax += v.x * w; ay += v.y * w; az += v.z * w; aw += v.w * w;
  }
  float iv = inv_in[n];
  float4 bb = *(const float4*)(bias + q * 4);
  float4 o;
  o.x = fmaxf(ax * iv + bb.x, 0.f);
  o.y = fmaxf(ay * iv + bb.y, 0.f);
  o.z = fmaxf(az * iv + bb.z, 0.f);
  o.w = fmaxf(aw * iv + bb.w, 0.f);
  *(float4*)(hout + (size_t)n * 96 + q * 4) = o;
}

// ---------- layer 2: CSR gather 16-dim + bias + log_softmax ----------
__global__ __launch_bounds__(256) void gather16_lsm_kernel(
    const float* __restrict__ Y2, const uint32_t* __restrict__ csr,
    const int* __restrict__ row_ptr, const float* __restrict__ inv_in,
    const float* __restrict__ b2, float* __restrict__ out) {
  int n = blockIdx.x * 256 + threadIdx.x;
  if (n >= NNODES) return;
  int beg = row_ptr[n], end = row_ptr[n + 1];
  float4 a0 = {0,0,0,0}, a1 = {0,0,0,0}, a2 = {0,0,0,0}, a3 = {0,0,0,0};
  for (int p = beg; p < end; ++p) {
    uint32_t pr = csr[p];
    int s = pr >> 16;
    float w = __half2float(__ushort_as_half((unsigned short)(pr & 0xFFFFu)));
    const float4* y = (const float4*)(Y2 + (size_t)s * 16);
    float4 y0 = y[0], y1 = y[1], y2 = y[2], y3 = y[3];
    a0.x += y0.x * w; a0.y += y0.y * w; a0.z += y0.z * w; a0.w += y0.w * w;
    a1.x += y1.x * w; a1.y += y1.y * w; a1.z += y1.z * w; a1.w += y1.w * w;
    a2.x += y2.x * w; a2.y += y2.y * w; a2.z += y2.z * w; a2.w += y2.w * w;
    a3.x += y3.x * w; a3.y += y3.y * w; a3.z += y3.z * w; a3.w += y3.w * w;
  }
  float iv = inv_in[n];
  float v[16];
  v[0]  = a0.x * iv + b2[0];  v[1]  = a0.y * iv + b2[1];
  v[2]  = a0.z * iv + b2[2];  v[3]  = a0.w * iv + b2[3];
  v[4]  = a1.x * iv + b2[4];  v[5]  = a1.y * iv + b2[5];
  v[6]  = a1.z * iv + b2[6];  v[7]  = a1.w * iv + b2[7];
  v[8]  = a2.x * iv + b2[8];  v[9]  = a2.y * iv + b2[9];
  v[10] = a2.z * iv + b2[10]; v[11] = a2.w * iv + b2[11];
  v[12] = a3.x * iv + b2[12]; v[13] = a3.y * iv + b2[13];
  v[14] = a3.z * iv + b2[14]; v[15] = a3.w * iv + b2[15];
  float m = v[0];
#pragma unroll
  for (int i = 1; i < 16; i++) m = fmaxf(m, v[i]);
  float s = 0.f;
#pragma unroll
  for (int i = 0; i < 16; i++) s += expf(v[i] - m);
  float ls = logf(s);
  float* orow = out + (size_t)n * 16;
#pragma unroll
  for (int i = 0; i < 16; i++) orow[i] = v[i] - m - ls;
}

extern "C" void kernel_launch(void* const* d_in, const int* in_sizes, int n_in,
                              void* d_out, int out_size, void* d_ws, size_t ws_size,
                              hipStream_t stream) {
  const float* feat = (const float*)d_in[0];
  const float* ew   = (const float*)d_in[1];
  const int*   src  = (const int*)d_in[2];
  const int*   dst  = (const int*)d_in[3];
  const float* W0   = (const float*)d_in[4];
  const float* b0   = (const float*)d_in[5];
  const float* W1   = (const float*)d_in[6];
  const float* b1   = (const float*)d_in[7];
  const float* W2   = (const float*)d_in[8];
  const float* b2   = (const float*)d_in[9];
  float* out = (float*)d_out;

  char* base = (char*)d_ws;
  size_t off = 0;
  auto take = [&](size_t nbytes) {
    void* q = base + off;
    off += (nbytes + 255) & ~(size_t)255;
    return q;
  };
  int*      odeg    = (int*)take((size_t)NNODES * 4);
  int*      ideg    = (int*)take((size_t)NNODES * 4);
  int*      row_ptr = (int*)take((size_t)(NNODES + 1) * 4);
  int*      bsum    = (int*)take((size_t)NB * 4);
  int*      boff    = (int*)take((size_t)NB * 4);
  float*    inv_o   = (float*)take((size_t)NNODES * 4);
  float*    inv_i   = (float*)take((size_t)NNODES * 4);
  int*      slot    = (int*)take((size_t)NEDGES * 4);
  uint32_t* csr     = (uint32_t*)take((size_t)NEDGES * 4);
  float*    A       = (float*)take((size_t)NNODES * NHID * 4);
  float*    B       = (float*)take((size_t)NNODES * NHID * 4);
  float*    Y2      = (float*)take((size_t)NNODES * NCLS * 4);
  (void)ws_size; (void)in_sizes; (void)n_in; (void)out_size;

  uint32_t k[3][2];
  for (uint32_t i = 0; i < 3; i++) tf2x32(0u, 42u, 0u, i, k[i][0], k[i][1]);

  hipMemsetAsync(odeg, 0, (size_t)NNODES * 4, stream);
  hipMemsetAsync(ideg, 0, (size_t)NNODES * 4, stream);
  count_kernel<<<(NEDGES + 255) / 256, 256, 0, stream>>>(src, dst, odeg, ideg, slot);
  scan_blocks_kernel<<<NB, 256, 0, stream>>>(ideg, bsum);
  scan_top_kernel<<<1, 256, 0, stream>>>(bsum, boff);
  scan_write_kernel<<<NB, 256, 0, stream>>>(ideg, boff, row_ptr);
  inv_kernel<<<(NNODES + 255) / 256, 256, 0, stream>>>(odeg, ideg, inv_o, inv_i);
  fill2_kernel<<<(NEDGES + 255) / 256, 256, 0, stream>>>(src, dst, ew, row_ptr, slot, csr);

  const int NELEM = NNODES * NHID;
  const int G96 = (NNODES + 127) / 128;
  const int G16 = (NNODES + 511) / 512;

  // layer 0: feat -> A(dropped) -> B(gemm) -> A(h1)
  drop_kernel<<<(NELEM + 255) / 256, 256, 0, stream>>>(feat, inv_o, A, k[0][0], k[0][1]);
  gemm96_kernel<<<G96, 256, 0, stream>>>(A, W0, B);
  gather96_kernel<<<(NNODES * 24 + 255) / 256, 256, 0, stream>>>(B, csr, row_ptr, inv_i, b0, A);
  // layer 1: A -> B -> A -> B(h2)
  drop_kernel<<<(NELEM + 255) / 256, 256, 0, stream>>>(A, inv_o, B, k[1][0], k[1][1]);
  gemm96_kernel<<<G96, 256, 0, stream>>>(B, W1, A);
  gather96_kernel<<<(NNODES * 24 + 255) / 256, 256, 0, stream>>>(A, csr, row_ptr, inv_i, b1, B);
  // layer 2: B -> A -> Y2 -> out
  drop_kernel<<<(NELEM + 255) / 256, 256, 0, stream>>>(B, inv_o, A, k[2][0], k[2][1]);
  gemm16_kernel<<<G16, 256, 0, stream>>>(A, W2, Y2);
  gather16_lsm_kernel<<<(NNODES + 255) / 256, 256, 0, stream>>>(Y2, csr, row_ptr, inv_i, b2, out);
}

// Round 5
// 352.849 us; speedup vs baseline: 1.3633x; 1.1429x over previous
//
#include <hip/hip_runtime.h>
#include <hip/hip_fp16.h>
#include <stdint.h>

#define NNODES 50000
#define NEDGES 800000
#define NHID 96
#define NCLS 16
#define NB ((NNODES + 255) / 256)   // 196 scan blocks

// ---------- JAX Threefry-2x32 (Random123 20-round, matches jax._src.prng) ----------
__host__ __device__ inline void tf2x32(uint32_t k0, uint32_t k1, uint32_t x0, uint32_t x1,
                                       uint32_t& o0, uint32_t& o1) {
  uint32_t k2 = k0 ^ k1 ^ 0x1BD11BDAu;
#define TFROT(v, r) (((v) << (r)) | ((v) >> (32 - (r))))
#define TFR(r) { x0 += x1; x1 = TFROT(x1, r); x1 ^= x0; }
  x0 += k0; x1 += k1;
  TFR(13) TFR(15) TFR(26) TFR(6)
  x0 += k1; x1 += k2 + 1u;
  TFR(17) TFR(29) TFR(16) TFR(24)
  x0 += k2; x1 += k0 + 2u;
  TFR(13) TFR(15) TFR(26) TFR(6)
  x0 += k0; x1 += k1 + 3u;
  TFR(17) TFR(29) TFR(16) TFR(24)
  x0 += k1; x1 += k2 + 4u;
  TFR(13) TFR(15) TFR(26) TFR(6)
  x0 += k2; x1 += k0 + 5u;
  o0 = x0; o1 = x1;
#undef TFR
#undef TFROT
}

__device__ inline bool keep_bit(uint32_t k0, uint32_t k1, uint32_t j) {
  uint32_t o0, o1;
  tf2x32(k0, k1, 0u, j, o0, o1);
  return (((o0 ^ o1) >> 31) == 0u);   // uniform<0.5 <=> MSB==0
}

// ---------- pass 1: degrees + per-edge slot (CSR local index) ----------
__global__ __launch_bounds__(256) void count_kernel(
    const int* __restrict__ src, const int* __restrict__ dst,
    int* __restrict__ odeg, int* __restrict__ ideg, int* __restrict__ slot) {
  int e = blockIdx.x * 256 + threadIdx.x;
  if (e >= NEDGES) return;
  atomicAdd(&odeg[src[e]], 1);
  slot[e] = atomicAdd(&ideg[dst[e]], 1);
}

// ---------- hierarchical exclusive scan of ideg -> row_ptr ----------
__global__ __launch_bounds__(256) void scan_blocks_kernel(
    const int* __restrict__ ideg, int* __restrict__ bsum) {
  __shared__ int lds[256];
  const int tid = threadIdx.x;
  int i = blockIdx.x * 256 + tid;
  lds[tid] = (i < NNODES) ? ideg[i] : 0;
  __syncthreads();
  for (int off = 128; off > 0; off >>= 1) {
    if (tid < off) lds[tid] += lds[tid + off];
    __syncthreads();
  }
  if (tid == 0) bsum[blockIdx.x] = lds[0];
}

__global__ __launch_bounds__(256) void scan_top_kernel(
    const int* __restrict__ bsum, int* __restrict__ boff) {
  __shared__ int lds[256];
  const int tid = threadIdx.x;
  int v = (tid < NB) ? bsum[tid] : 0;
  lds[tid] = v;
  __syncthreads();
  for (int off = 1; off < 256; off <<= 1) {
    int t = (tid >= off) ? lds[tid - off] : 0;
    __syncthreads();
    lds[tid] += t;
    __syncthreads();
  }
  if (tid < NB) boff[tid] = lds[tid] - v;   // exclusive
}

__global__ __launch_bounds__(256) void scan_write_kernel(
    const int* __restrict__ ideg, const int* __restrict__ boff,
    int* __restrict__ row_ptr) {
  __shared__ int lds[256];
  const int tid = threadIdx.x;
  int i = blockIdx.x * 256 + tid;
  int v = (i < NNODES) ? ideg[i] : 0;
  lds[tid] = v;
  __syncthreads();
  for (int off = 1; off < 256; off <<= 1) {
    int t = (tid >= off) ? lds[tid - off] : 0;
    __syncthreads();
    lds[tid] += t;
    __syncthreads();
  }
  if (i < NNODES) row_ptr[i] = boff[blockIdx.x] + lds[tid] - v;
  if (i == 0) row_ptr[NNODES] = NEDGES;
}

__global__ __launch_bounds__(256) void inv_kernel(
    const int* __restrict__ odeg, const int* __restrict__ ideg,
    float* __restrict__ inv_o, float* __restrict__ inv_i) {
  int n = blockIdx.x * 256 + threadIdx.x;
  if (n >= NNODES) return;
  inv_o[n] = rsqrtf(fmaxf((float)odeg[n], 1.0f));
  inv_i[n] = rsqrtf(fmaxf((float)ideg[n], 1.0f));
}

// ---------- pass 2: atomic-free scatter into dense packed CSR ----------
// packed weight w' = ew * 2 * inv_o[src]  (dropout 1/(1-p) and D_out^-1/2 folded in)
__global__ __launch_bounds__(256) void fill2_kernel(
    const int* __restrict__ src, const int* __restrict__ dst, const float* __restrict__ ew,
    const int* __restrict__ row_ptr, const int* __restrict__ slot,
    const float* __restrict__ inv_o, uint32_t* __restrict__ csr) {
  int e = blockIdx.x * 256 + threadIdx.x;
  if (e >= NEDGES) return;
  int s = src[e];
  float wp = ew[e] * 2.0f * inv_o[s];
  int pos = row_ptr[dst[e]] + slot[e];
  csr[pos] = ((uint32_t)s << 16) | (uint32_t)__half_as_ushort(__float2half_rn(wp));
}

// ---------- layer-0 dropout: pure mask (scale folded into CSR weight) ----------
__global__ __launch_bounds__(256) void drop0_kernel(
    const float* __restrict__ h, float* __restrict__ X, uint32_t k0, uint32_t k1) {
  int j = blockIdx.x * 256 + threadIdx.x;
  if (j >= NNODES * NHID) return;
  X[j] = keep_bit(k0, k1, (uint32_t)j) ? h[j] : 0.0f;
}

// ---------- GEMM96: Yh[N,96](fp16) = X[N,96](fp32) @ W[96,96], LDS-staged W ----------
__global__ __launch_bounds__(256) void gemm96_kernel(
    const float* __restrict__ X, const float* __restrict__ W, __half* __restrict__ Yh) {
  __shared__ float Wl[96 * 96];
  const int tid = threadIdx.x;
  {
    const float4* Wg = (const float4*)W;
    float4* Ws = (float4*)Wl;
#pragma unroll
    for (int i = 0; i < 9; ++i)
      Ws[tid + i * 256] = Wg[tid + i * 256];
  }
  __syncthreads();

  const int cg = tid & 7;
  const int rq = tid >> 3;
  const int row0 = blockIdx.x * 128 + rq * 4;
  const int c0 = cg * 12;

  float acc[4][12];
#pragma unroll
  for (int r = 0; r < 4; ++r)
#pragma unroll
    for (int c = 0; c < 12; ++c) acc[r][c] = 0.f;

  const float* xr[4];
#pragma unroll
  for (int r = 0; r < 4; ++r) {
    int rr = row0 + r; if (rr > NNODES - 1) rr = NNODES - 1;
    xr[r] = X + (size_t)rr * 96;
  }

  for (int k = 0; k < 96; k += 4) {
    float4 x4[4];
#pragma unroll
    for (int r = 0; r < 4; ++r) x4[r] = *(const float4*)(xr[r] + k);
#pragma unroll
    for (int kk = 0; kk < 4; ++kk) {
      const float4* wp = (const float4*)(Wl + (k + kk) * 96 + c0);
      float4 w0 = wp[0], w1 = wp[1], w2 = wp[2];
      float xv[4] = { (&x4[0].x)[kk], (&x4[1].x)[kk], (&x4[2].x)[kk], (&x4[3].x)[kk] };
#pragma unroll
      for (int r = 0; r < 4; ++r) {
        acc[r][0]  += xv[r] * w0.x; acc[r][1]  += xv[r] * w0.y;
        acc[r][2]  += xv[r] * w0.z; acc[r][3]  += xv[r] * w0.w;
        acc[r][4]  += xv[r] * w1.x; acc[r][5]  += xv[r] * w1.y;
        acc[r][6]  += xv[r] * w1.z; acc[r][7]  += xv[r] * w1.w;
        acc[r][8]  += xv[r] * w2.x; acc[r][9]  += xv[r] * w2.y;
        acc[r][10] += xv[r] * w2.z; acc[r][11] += xv[r] * w2.w;
      }
    }
  }

#pragma unroll
  for (int r = 0; r < 4; ++r) {
    int rr = row0 + r;
    if (rr < NNODES) {
      __half2* hp = (__half2*)(Yh + (size_t)rr * 96 + c0);
#pragma unroll
      for (int c = 0; c < 6; ++c)
        hp[c] = __floats2half2_rn(acc[r][2 * c], acc[r][2 * c + 1]);
    }
  }
}

// ---------- GEMM16: Y2h[N,16](fp16) = X[N,96] @ W[96,16], LDS-staged W ----------
__global__ __launch_bounds__(256) void gemm16_kernel(
    const float* __restrict__ X, const float* __restrict__ W, __half* __restrict__ Y2h) {
  __shared__ float Wl[96 * 16];
  const int tid = threadIdx.x;
  {
    const float4* Wg = (const float4*)W;
    float4* Ws = (float4*)Wl;
    for (int i = tid; i < 384; i += 256) Ws[i] = Wg[i];
  }
  __syncthreads();

  const int row0 = blockIdx.x * 512 + tid * 2;
  const float* xr[2];
#pragma unroll
  for (int r = 0; r < 2; ++r) {
    int rr = row0 + r; if (rr > NNODES - 1) rr = NNODES - 1;
    xr[r] = X + (size_t)rr * 96;
  }

  float acc[2][16];
#pragma unroll
  for (int r = 0; r < 2; ++r)
#pragma unroll
    for (int c = 0; c < 16; ++c) acc[r][c] = 0.f;

  for (int k = 0; k < 96; k += 4) {
    float4 x4[2];
#pragma unroll
    for (int r = 0; r < 2; ++r) x4[r] = *(const float4*)(xr[r] + k);
#pragma unroll
    for (int kk = 0; kk < 4; ++kk) {
      const float4* wp = (const float4*)(Wl + (k + kk) * 16);
      float4 w0 = wp[0], w1 = wp[1], w2 = wp[2], w3 = wp[3];
#pragma unroll
      for (int r = 0; r < 2; ++r) {
        float xv = (&x4[r].x)[kk];
        acc[r][0]  += xv * w0.x; acc[r][1]  += xv * w0.y;
        acc[r][2]  += xv * w0.z; acc[r][3]  += xv * w0.w;
        acc[r][4]  += xv * w1.x; acc[r][5]  += xv * w1.y;
        acc[r][6]  += xv * w1.z; acc[r][7]  += xv * w1.w;
        acc[r][8]  += xv * w2.x; acc[r][9]  += xv * w2.y;
        acc[r][10] += xv * w2.z; acc[r][11] += xv * w2.w;
        acc[r][12] += xv * w3.x; acc[r][13] += xv * w3.y;
        acc[r][14] += xv * w3.z; acc[r][15] += xv * w3.w;
      }
    }
  }

#pragma unroll
  for (int r = 0; r < 2; ++r) {
    int rr = row0 + r;
    if (rr < NNODES) {
      __half2* hp = (__half2*)(Y2h + (size_t)rr * 16);
#pragma unroll
      for (int c = 0; c < 8; ++c)
        hp[c] = __floats2half2_rn(acc[r][2 * c], acc[r][2 * c + 1]);
    }
  }
}

// ---------- CSR gather (fp16 Y) + inv_in*bias + ReLU + next-layer dropout mask ----------
// thread = (node n, chunk q of 8 dims); writes X_next (fp32) directly.
__global__ __launch_bounds__(256) void gather96_drop_kernel(
    const __half* __restrict__ Yh, const uint32_t* __restrict__ csr,
    const int* __restrict__ row_ptr, const float* __restrict__ inv_in,
    const float* __restrict__ bias, float* __restrict__ Xn,
    uint32_t k0, uint32_t k1) {
  int tid = blockIdx.x * 256 + threadIdx.x;
  int n = tid / 12;
  int q = tid - n * 12;        // 8-dim chunk within the 96-dim row
  if (n >= NNODES) return;
  int beg = row_ptr[n], end = row_ptr[n + 1];
  float acc[8];
#pragma unroll
  for (int i = 0; i < 8; ++i) acc[i] = 0.f;
  for (int p = beg; p < end; ++p) {
    uint32_t pr = csr[p];
    int s = pr >> 16;
    float w = __half2float(__ushort_as_half((unsigned short)(pr & 0xFFFFu)));
    uint4 u = *(const uint4*)(Yh + (size_t)s * 96 + q * 8);
    float2 f0 = __half22float2(*(__half2*)&u.x);
    float2 f1 = __half22float2(*(__half2*)&u.y);
    float2 f2 = __half22float2(*(__half2*)&u.z);
    float2 f3 = __half22float2(*(__half2*)&u.w);
    acc[0] += f0.x * w; acc[1] += f0.y * w;
    acc[2] += f1.x * w; acc[3] += f1.y * w;
    acc[4] += f2.x * w; acc[5] += f2.y * w;
    acc[6] += f3.x * w; acc[7] += f3.y * w;
  }
  float iv = inv_in[n];
  float4 b0 = *(const float4*)(bias + q * 8);
  float4 b1 = *(const float4*)(bias + q * 8 + 4);
  float o[8];
  o[0] = fmaxf(acc[0] * iv + b0.x, 0.f);
  o[1] = fmaxf(acc[1] * iv + b0.y, 0.f);
  o[2] = fmaxf(acc[2] * iv + b0.z, 0.f);
  o[3] = fmaxf(acc[3] * iv + b0.w, 0.f);
  o[4] = fmaxf(acc[4] * iv + b1.x, 0.f);
  o[5] = fmaxf(acc[5] * iv + b1.y, 0.f);
  o[6] = fmaxf(acc[6] * iv + b1.z, 0.f);
  o[7] = fmaxf(acc[7] * iv + b1.w, 0.f);
  uint32_t jb = (uint32_t)(n * 96 + q * 8);
#pragma unroll
  for (int i = 0; i < 8; ++i)
    o[i] = keep_bit(k0, k1, jb + i) ? o[i] : 0.f;
  float* xp = Xn + (size_t)n * 96 + q * 8;
  *(float4*)(xp + 0) = make_float4(o[0], o[1], o[2], o[3]);
  *(float4*)(xp + 4) = make_float4(o[4], o[5], o[6], o[7]);
}

// ---------- layer 2: CSR gather (fp16 Y2) + bias + log_softmax ----------
__global__ __launch_bounds__(256) void gather16_lsm_kernel(
    const __half* __restrict__ Y2h, const uint32_t* __restrict__ csr,
    const int* __restrict__ row_ptr, const float* __restrict__ inv_in,
    const float* __restrict__ b2, float* __restrict__ out) {
  int n = blockIdx.x * 256 + threadIdx.x;
  if (n >= NNODES) return;
  int beg = row_ptr[n], end = row_ptr[n + 1];
  float acc[16];
#pragma unroll
  for (int i = 0; i < 16; ++i) acc[i] = 0.f;
  for (int p = beg; p < end; ++p) {
    uint32_t pr = csr[p];
    int s = pr >> 16;
    float w = __half2float(__ushort_as_half((unsigned short)(pr & 0xFFFFu)));
    const uint4* yp = (const uint4*)(Y2h + (size_t)s * 16);
    uint4 ua = yp[0], ub = yp[1];
    float2 f0 = __half22float2(*(__half2*)&ua.x);
    float2 f1 = __half22float2(*(__half2*)&ua.y);
    float2 f2 = __half22float2(*(__half2*)&ua.z);
    float2 f3 = __half22float2(*(__half2*)&ua.w);
    float2 f4 = __half22float2(*(__half2*)&ub.x);
    float2 f5 = __half22float2(*(__half2*)&ub.y);
    float2 f6 = __half22float2(*(__half2*)&ub.z);
    float2 f7 = __half22float2(*(__half2*)&ub.w);
    acc[0]  += f0.x * w; acc[1]  += f0.y * w;
    acc[2]  += f1.x * w; acc[3]  += f1.y * w;
    acc[4]  += f2.x * w; acc[5]  += f2.y * w;
    acc[6]  += f3.x * w; acc[7]  += f3.y * w;
    acc[8]  += f4.x * w; acc[9]  += f4.y * w;
    acc[10] += f5.x * w; acc[11] += f5.y * w;
    acc[12] += f6.x * w; acc[13] += f6.y * w;
    acc[14] += f7.x * w; acc[15] += f7.y * w;
  }
  float iv = inv_in[n];
  float v[16];
#pragma unroll
  for (int i = 0; i < 16; ++i) v[i] = acc[i] * iv + b2[i];
  float m = v[0];
#pragma unroll
  for (int i = 1; i < 16; i++) m = fmaxf(m, v[i]);
  float s = 0.f;
#pragma unroll
  for (int i = 0; i < 16; i++) s += expf(v[i] - m);
  float ls = logf(s);
  float* orow = out + (size_t)n * 16;
#pragma unroll
  for (int i = 0; i < 16; i++) orow[i] = v[i] - m - ls;
}

extern "C" void kernel_launch(void* const* d_in, const int* in_sizes, int n_in,
                              void* d_out, int out_size, void* d_ws, size_t ws_size,
                              hipStream_t stream) {
  const float* feat = (const float*)d_in[0];
  const float* ew   = (const float*)d_in[1];
  const int*   src  = (const int*)d_in[2];
  const int*   dst  = (const int*)d_in[3];
  const float* W0   = (const float*)d_in[4];
  const float* b0   = (const float*)d_in[5];
  const float* W1   = (const float*)d_in[6];
  const float* b1   = (const float*)d_in[7];
  const float* W2   = (const float*)d_in[8];
  const float* b2   = (const float*)d_in[9];
  float* out = (float*)d_out;

  char* base = (char*)d_ws;
  size_t off = 0;
  auto take = [&](size_t nbytes) {
    void* q = base + off;
    off += (nbytes + 255) & ~(size_t)255;
    return q;
  };
  int*      odeg    = (int*)take((size_t)NNODES * 4);
  int*      ideg    = (int*)take((size_t)NNODES * 4);
  int*      row_ptr = (int*)take((size_t)(NNODES + 1) * 4);
  int*      bsum    = (int*)take((size_t)NB * 4);
  int*      boff    = (int*)take((size_t)NB * 4);
  float*    inv_o   = (float*)take((size_t)NNODES * 4);
  float*    inv_i   = (float*)take((size_t)NNODES * 4);
  int*      slot    = (int*)take((size_t)NEDGES * 4);
  uint32_t* csr     = (uint32_t*)take((size_t)NEDGES * 4);
  float*    X       = (float*)take((size_t)NNODES * NHID * 4);
  __half*   Yh      = (__half*)take((size_t)NNODES * NHID * 2);
  __half*   Y2h     = (__half*)take((size_t)NNODES * NCLS * 2);
  (void)ws_size; (void)in_sizes; (void)n_in; (void)out_size;

  uint32_t k[3][2];
  for (uint32_t i = 0; i < 3; i++) tf2x32(0u, 42u, 0u, i, k[i][0], k[i][1]);

  hipMemsetAsync(odeg, 0, (size_t)NNODES * 4, stream);
  hipMemsetAsync(ideg, 0, (size_t)NNODES * 4, stream);
  count_kernel<<<(NEDGES + 255) / 256, 256, 0, stream>>>(src, dst, odeg, ideg, slot);
  scan_blocks_kernel<<<NB, 256, 0, stream>>>(ideg, bsum);
  scan_top_kernel<<<1, 256, 0, stream>>>(bsum, boff);
  scan_write_kernel<<<NB, 256, 0, stream>>>(ideg, boff, row_ptr);
  inv_kernel<<<(NNODES + 255) / 256, 256, 0, stream>>>(odeg, ideg, inv_o, inv_i);
  fill2_kernel<<<(NEDGES + 255) / 256, 256, 0, stream>>>(src, dst, ew, row_ptr, slot, inv_o, csr);

  const int NELEM = NNODES * NHID;
  const int G96  = (NNODES + 127) / 128;
  const int G16  = (NNODES + 511) / 512;
  const int GGD  = (NNODES * 12 + 255) / 256;

  // layer 0: feat --mask0--> X --gemm--> Yh --gather+mask1--> X
  drop0_kernel<<<(NELEM + 255) / 256, 256, 0, stream>>>(feat, X, k[0][0], k[0][1]);
  gemm96_kernel<<<G96, 256, 0, stream>>>(X, W0, Yh);
  gather96_drop_kernel<<<GGD, 256, 0, stream>>>(Yh, csr, row_ptr, inv_i, b0, X, k[1][0], k[1][1]);
  // layer 1: X --gemm--> Yh --gather+mask2--> X
  gemm96_kernel<<<G96, 256, 0, stream>>>(X, W1, Yh);
  gather96_drop_kernel<<<GGD, 256, 0, stream>>>(Yh, csr, row_ptr, inv_i, b1, X, k[2][0], k[2][1]);
  // layer 2: X --gemm16--> Y2h --gather+lsm--> out
  gemm16_kernel<<<G16, 256, 0, stream>>>(X, W2, Y2h);
  gather16_lsm_kernel<<<(NNODES + 255) / 256, 256, 0, stream>>>(Y2h, csr, row_ptr, inv_i, b2, out);
}